// Round 3
// baseline (322.485 us; speedup 1.0000x reference)
//
#include <hip/hip_runtime.h>
#include <hip/hip_cooperative_groups.h>
#include <stdint.h>

namespace cg = cooperative_groups;

// Radius-graph edge list, B=4, N=2048, cutoff 5.0.
// Output [2, B*P] int32: compacted valid edges (ascending flat index), -1 pad.
//
// Round-9: single COOPERATIVE kernel. Rounds 1-2 proved the scatter-side work
// was never the slack (35-36 us vs 32.6 for 3 different scatter structures);
// the cost is per-dispatch overhead + the counts round-trip between two
// dispatches. Fuse: grid = 2047 blocks x 256 thr (= 8 blocks/CU x 256 CU
// co-residency, enforced by __launch_bounds__(256,8) -> VGPR<=64, ~3KB LDS),
// kItems=16 so 2047*4096 == kTotal exactly.
//   Phase A: -1 fill own slice (zero-dep stores), 16-item incremental pair
//            walk, ballot epilogue, counts[bid], stash edges in LDS (kCap=320;
//            LDS survives the grid barrier -> no global stash traffic).
//   grid.sync()
//   Phase B: each block reads all 2048 counts (8 KB, L2-hot), reduces its own
//            prefix, copies LDS stash to final positions. Overflow (>kCap):
//            two-pass ballot recompute, array-free (keeps VGPR low).
// Fallback: if hipLaunchCooperativeKernel is rejected (capture/capacity), the
// known-good round-0 two-kernel pipeline runs instead.

namespace {
constexpr int kB = 4;
constexpr int kN = 2048;
constexpr int kP = kN * (kN - 1) / 2;              // 2096128
constexpr long long kTotal = (long long)kB * kP;   // 8384512
constexpr int kBlock = 256;
constexpr float kCut2 = 25.0f;                     // 5.0^2

// Cooperative (fused) config.
constexpr int kItems = 16;
constexpr int kChunk = kBlock * kItems;            // 4096
constexpr int kGrid = (int)(kTotal / kChunk);      // 2047 (exact, <= 2048 resident)
constexpr int kCap = 320;                          // LDS stash slots per block

// Fallback (two-kernel) config.
constexpr int kFItems = 8;
constexpr int kFChunk = kBlock * kFItems;          // 2048
constexpr int kFNBlk = (int)(kTotal / kFChunk);    // 4094
constexpr int kFCap = 128;
}  // namespace

// p in [0,P) -> (i,j), i<j, triu row-major. Closed-form sqrt guess + exact
// integer fixup. C(i) = i*(4095-i)/2. disc < 2^24 so float sqrt is tight.
__device__ __forceinline__ void decode_pair(int p, int& i, int& j) {
  float t = sqrtf((float)(16769025 - 8 * p));
  int ii = (int)((4095.0f - t) * 0.5f);
  ii = ii < 0 ? 0 : (ii > kN - 2 ? kN - 2 : ii);
  while (ii > 0 && (ii * (4095 - ii)) / 2 > p) --ii;
  while (ii < kN - 2 && ((ii + 1) * (4094 - ii)) / 2 <= p) ++ii;
  i = ii;
  j = ii + 1 + (p - (ii * (4095 - ii)) / 2);
}

__device__ __forceinline__ bool pair_test(const float* __restrict__ x, int b, int p,
                                          int& gi, int& gj) {
  int i, j;
  decode_pair(p, i, j);
  const float* xb = x + (size_t)b * kN * 3;
  float dx = xb[3 * i + 0] - xb[3 * j + 0];
  float dy = xb[3 * i + 1] - xb[3 * j + 1];
  float dz = xb[3 * i + 2] - xb[3 * j + 2];
  gi = b * kN + i;
  gj = b * kN + j;
  return dx * dx + dy * dy + dz * dz <= kCut2;
}

// ---------------------------------------------------------------------------
// Fused cooperative kernel.
// ---------------------------------------------------------------------------
__global__ __launch_bounds__(kBlock, 8) void fused_kernel(
    const float* __restrict__ x, uint32_t* __restrict__ counts,
    int* __restrict__ out) {
  const int t = threadIdx.x;
  const int wave = t >> 6, lane = t & 63;
  const int bid = blockIdx.x;
  const int base = bid * kChunk;

  __shared__ uint32_t slot[kItems * 4];  // 64 (item,wave) counts / scan
  __shared__ int2 lstash[kCap];          // edges survive the grid barrier
  __shared__ uint32_t wred[4];
  __shared__ uint32_t total_sh;

  // ---- Phase A ----
  // -1 fill of this block's slice (4096 ints x 2 rows). Zero-dependency
  // stores: issue from cycle 0 and drain under the compute below.
  {
    const int4 m1 = make_int4(-1, -1, -1, -1);
    int4* o0 = (int4*)out + (base >> 2);
    int4* o1 = (int4*)(out + kTotal) + (base >> 2);
#pragma unroll
    for (int s = 0; s < 4; ++s) {
      o0[t + s * kBlock] = m1;
      o1[t + s * kBlock] = m1;
    }
  }
  if (bid == 0 && t == 0) counts[kGrid] = 0;  // pad -> 2048 uint4-loadable

  // One sqrt-decode per thread, then incremental row-walk (+256/item).
  int b = base / kP;
  int p = base - b * kP + t;
  if (p >= kP) { p -= kP; ++b; }
  int i, j;
  decode_pair(p, i, j);
  int ib = b * kN;

  const float3* __restrict__ x3 = (const float3*)x;
  float3 pi = x3[ib + i];

  uint32_t hits = 0;  // bit k = item k is an edge
#pragma unroll
  for (int k = 0; k < kItems; ++k) {
    float3 pj = x3[ib + j];
    float dx = pi.x - pj.x, dy = pi.y - pj.y, dz = pi.z - pj.z;
    if (dx * dx + dy * dy + dz * dz <= kCut2) hits |= (1u << k);
    if (k < kItems - 1) {
      j += kBlock;
      if (j >= kN) {  // row advance, mostly wave-coherent
        do {
          int ex = j - kN;
          ++i;
          if (i >= kN - 1) { i = 0; ib += kN; }
          j = i + 1 + ex;
        } while (j >= kN);
        pi = x3[ib + i];
      }
    }
  }

  if (t < kItems * 4) slot[t] = 0;
  __syncthreads();

  const bool waveany = (__ballot(hits != 0) != 0ULL);  // wave-uniform
  if (waveany) {
#pragma unroll
    for (int k = 0; k < kItems; ++k) {
      unsigned long long m = __ballot((hits >> k) & 1u);
      if (m != 0ULL && lane == 0) slot[k * 4 + wave] = (uint32_t)__popcll(m);
    }
  }
  __syncthreads();
  if (t < 64) {  // exclusive scan of 64 (item,wave) counts in one wave
    uint32_t v = slot[t];
    uint32_t run = v;
    for (int o = 1; o < 64; o <<= 1) {
      uint32_t u = __shfl_up(run, o, 64);
      if (lane >= o) run += u;
    }
    slot[t] = run - v;
    if (t == 63) {
      counts[bid] = run;
      total_sh = run;
    }
  }
  __syncthreads();
  if (waveany) {
#pragma unroll
    for (int k = 0; k < kItems; ++k) {
      bool f = (hits >> k) & 1u;
      unsigned long long m = __ballot(f);
      if (m != 0ULL && f) {  // rare: ~6 hits per block expected
        int pf = base + k * kBlock + t;
        int hb = pf / kP;
        int hp = pf - hb * kP;
        int hi, hj;
        decode_pair(hp, hi, hj);
        uint32_t pos = slot[k * 4 + wave] +
                       (uint32_t)__popcll(m & ((1ULL << lane) - 1ULL));
        if (pos < (uint32_t)kCap)
          lstash[pos] = make_int2(hb * kN + hi, hb * kN + hj);
      }
    }
  }

  cg::this_grid().sync();

  // ---- Phase B ----
  // Own offset: sum(counts[idx < bid]) over 2048 entries (8 KB, L2-hot).
  const uint4* c4 = (const uint4*)counts;
  uint32_t below = 0;
#pragma unroll
  for (int q = 0; q < 2; ++q) {
    uint4 v = c4[t * 2 + q];
    int i0 = t * 8 + q * 4;
    below += (i0 + 0 < bid) ? v.x : 0u;
    below += (i0 + 1 < bid) ? v.y : 0u;
    below += (i0 + 2 < bid) ? v.z : 0u;
    below += (i0 + 3 < bid) ? v.w : 0u;
  }
  for (int o = 32; o > 0; o >>= 1) below += __shfl_down(below, o, 64);
  if (lane == 0) wred[wave] = below;
  __syncthreads();
  const uint32_t off = wred[0] + wred[1] + wred[2] + wred[3];
  const uint32_t cnt = total_sh;  // block-uniform
  if (cnt == 0) return;

  if (cnt <= (uint32_t)kCap) {
    for (uint32_t e = t; e < cnt; e += kBlock) {
      int2 v = lstash[e];
      out[off + e] = v.x;
      out[(size_t)kTotal + off + e] = v.y;
    }
    return;
  }
  // Overflow fallback (cnt > kCap): two-pass array-free ballot recompute.
  for (int k = 0; k < kItems; ++k) {
    int pf = base + k * kBlock + t;
    int hb = pf / kP, hp = pf - hb * kP;
    int gi_, gj_;
    bool f = pair_test(x, hb, hp, gi_, gj_);
    unsigned long long m = __ballot(f);
    if (lane == 0) slot[k * 4 + wave] = (uint32_t)__popcll(m);
  }
  __syncthreads();
  if (t == 0) {
    uint32_t run = off;
    for (int s = 0; s < kItems * 4; ++s) {
      uint32_t c = slot[s];
      slot[s] = run;
      run += c;
    }
  }
  __syncthreads();
  for (int k = 0; k < kItems; ++k) {
    int pf = base + k * kBlock + t;
    int hb = pf / kP, hp = pf - hb * kP;
    int gi_, gj_;
    bool f = pair_test(x, hb, hp, gi_, gj_);
    unsigned long long m = __ballot(f);
    if (f) {
      uint32_t pos = slot[k * 4 + wave] +
                     (uint32_t)__popcll(m & ((1ULL << lane) - 1ULL));
      out[pos] = gi_;
      out[(size_t)kTotal + pos] = gj_;
    }
  }
}

// ---------------------------------------------------------------------------
// Fallback: known-good round-0 two-kernel pipeline (runs only if the
// cooperative launch is rejected).
// ---------------------------------------------------------------------------
__global__ __launch_bounds__(kBlock) void pass1_kernel(const float* __restrict__ x,
                                                       uint32_t* __restrict__ counts,
                                                       int2* __restrict__ stash,
                                                       int* __restrict__ out) {
  const int t = threadIdx.x;
  const int wave = t >> 6, lane = t & 63;
  const int bid = blockIdx.x;
  const int base = bid * kFChunk;

  {
    const int4 m1 = make_int4(-1, -1, -1, -1);
    int4* o0 = (int4*)out + (base >> 2);
    int4* o1 = (int4*)(out + kTotal) + (base >> 2);
    o0[t] = m1;
    o0[t + kBlock] = m1;
    o1[t] = m1;
    o1[t + kBlock] = m1;
  }
  if (bid == 0 && t < 2) counts[kFNBlk + t] = 0;

  int b = base / kP;
  int p = base - b * kP + t;
  if (p >= kP) { p -= kP; ++b; }
  int i, j;
  decode_pair(p, i, j);
  int ib = b * kN;

  const float3* __restrict__ x3 = (const float3*)x;
  float3 pi = x3[ib + i];

  uint32_t hits = 0;
#pragma unroll
  for (int k = 0; k < kFItems; ++k) {
    float3 pj = x3[ib + j];
    float dx = pi.x - pj.x, dy = pi.y - pj.y, dz = pi.z - pj.z;
    if (dx * dx + dy * dy + dz * dz <= kCut2) hits |= (1u << k);
    if (k < kFItems - 1) {
      j += kBlock;
      if (j >= kN) {
        do {
          int ex = j - kN;
          ++i;
          if (i >= kN - 1) { i = 0; ib += kN; }
          j = i + 1 + ex;
        } while (j >= kN);
        pi = x3[ib + i];
      }
    }
  }

  __shared__ uint32_t slot[32];
  if (t < 32) slot[t] = 0;
  __syncthreads();

  const bool waveany = (__ballot(hits != 0) != 0ULL);
  if (waveany) {
#pragma unroll
    for (int k = 0; k < kFItems; ++k) {
      unsigned long long m = __ballot((hits >> k) & 1u);
      if (m != 0ULL && lane == 0) slot[k * 4 + wave] = (uint32_t)__popcll(m);
    }
  }
  __syncthreads();
  if (t < 32) {
    uint32_t v = slot[t];
    uint32_t run = v;
    for (int off = 1; off < 32; off <<= 1) {
      uint32_t u = __shfl_up(run, off, 64);
      if (t >= off) run += u;
    }
    slot[t] = run - v;
    if (t == 31) counts[bid] = run;
  }
  __syncthreads();
  if (waveany) {
#pragma unroll
    for (int k = 0; k < kFItems; ++k) {
      bool f = (hits >> k) & 1u;
      unsigned long long m = __ballot(f);
      if (m != 0ULL && f) {
        int pf = base + k * kBlock + t;
        int hb = pf / kP;
        int hp = pf - hb * kP;
        int hi, hj;
        decode_pair(hp, hi, hj);
        uint32_t pos = slot[k * 4 + wave] +
                       (uint32_t)__popcll(m & ((1ULL << lane) - 1ULL));
        if (pos < (uint32_t)kFCap)
          stash[(size_t)bid * kFCap + pos] = make_int2(hb * kN + hi, hb * kN + hj);
      }
    }
  }
}

__global__ __launch_bounds__(kBlock) void scatter_kernel(const float* __restrict__ x,
                                                         const uint32_t* __restrict__ counts,
                                                         const int2* __restrict__ stash,
                                                         int* __restrict__ out) {
  const int bid = blockIdx.x;
  const int t = threadIdx.x;
  const int wave = t >> 6, lane = t & 63;

  const uint4* c4 = (const uint4*)counts;  // [4096] incl. zero pad
  uint32_t part = 0;
#pragma unroll
  for (int q = 0; q < 4; ++q) {
    uint4 v = c4[t * 4 + q];
    int i0 = t * 16 + q * 4;
    part += (i0 + 0 < bid) ? v.x : 0u;
    part += (i0 + 1 < bid) ? v.y : 0u;
    part += (i0 + 2 < bid) ? v.z : 0u;
    part += (i0 + 3 < bid) ? v.w : 0u;
  }
  for (int o = 32; o > 0; o >>= 1) part += __shfl_down(part, o, 64);
  __shared__ uint32_t wred[4];
  if ((t & 63) == 0) wred[t >> 6] = part;
  __syncthreads();
  if (t == 0) wred[0] = wred[0] + wred[1] + wred[2] + wred[3];
  __syncthreads();
  const uint32_t off = wred[0];
  const uint32_t cnt = counts[bid];
  if (cnt == 0) return;

  if (cnt <= (uint32_t)kFCap) {
    for (uint32_t e = t; e < cnt; e += kBlock) {
      int2 v = stash[(size_t)bid * kFCap + e];
      out[off + e] = v.x;
      out[(size_t)kTotal + off + e] = v.y;
    }
    return;
  }
  const int base = bid * kFChunk;
  const int bb0 = base / kP;
  const int p0 = base - bb0 * kP;
  __shared__ uint32_t slot[kFItems * 4];
  unsigned long long masks[kFItems];
  int gi[kFItems], gj[kFItems];
  bool fl[kFItems];
  for (int k = 0; k < kFItems; ++k) {
    int o = k * kBlock + t;
    int b = bb0, p = p0 + o;
    if (p >= kP) { p -= kP; ++b; }
    fl[k] = pair_test(x, b, p, gi[k], gj[k]);
    masks[k] = __ballot(fl[k]);
    if (lane == 0) slot[k * 4 + wave] = (uint32_t)__popcll(masks[k]);
  }
  __syncthreads();
  if (t == 0) {
    uint32_t run = 0;
    for (int s = 0; s < kFItems * 4; ++s) {
      uint32_t c = slot[s];
      slot[s] = run;
      run += c;
    }
  }
  __syncthreads();
  for (int k = 0; k < kFItems; ++k) {
    if (fl[k]) {
      uint32_t pos = off + slot[k * 4 + wave] +
                     (uint32_t)__popcll(masks[k] & ((1ULL << lane) - 1ULL));
      out[pos] = gi[k];
      out[(size_t)kTotal + pos] = gj[k];
    }
  }
}

extern "C" void kernel_launch(void* const* d_in, const int* in_sizes, int n_in,
                              void* d_out, int out_size, void* d_ws, size_t ws_size,
                              hipStream_t stream) {
  const float* x = (const float*)d_in[0];
  int* out = (int*)d_out;
  uint32_t* counts = (uint32_t*)d_ws;  // coop: [2048]; fallback: [4096]

  void* args[] = {(void*)&x, (void*)&counts, (void*)&out};
  hipError_t err = hipLaunchCooperativeKernel((const void*)fused_kernel,
                                              dim3(kGrid), dim3(kBlock), args, 0,
                                              stream);
  if (err != hipSuccess) {
    // Known-good two-kernel fallback (round-0 pipeline).
    int2* stash = (int2*)(counts + 4096);  // [4094 * kFCap] ~4.2 MB in ws
    hipLaunchKernelGGL(pass1_kernel, dim3(kFNBlk), dim3(kBlock), 0, stream, x,
                       counts, stash, out);
    hipLaunchKernelGGL(scatter_kernel, dim3(kFNBlk), dim3(kBlock), 0, stream, x,
                       counts, stash, out);
  }
}

// Round 5
// 233.353 us; speedup vs baseline: 1.3820x; 1.3820x over previous
//
#include <hip/hip_runtime.h>
#include <stdint.h>

// Radius-graph edge list, B=4, N=2048, cutoff 5.0.
// Output [2, B*P] int32: compacted valid edges (ascending flat index), -1 pad.
//
// Round-10b: SINGLE normal dispatch + last-block finisher. (Round-10a failed
// to compile: __builtin_nontemporal_store requires a native clang vector, not
// HIP_vector_type int4 -> use ext_vector_type(4) int.)
//   - Round-3 proved cg::grid.sync() is a disaster on 8 XCDs (286 us: L2
//     flush -> FETCH 47 MB, WRITE 158 MB, waves spinning at 4.5% VALUBusy).
//   - Rounds 1-2 proved scatter-side surgery doesn't move the total; the
//     slack is the second dispatch's drain+ramp, not its work.
//   So: phase A (validated round-3 structure, kItems=16, 2047 blocks) writes
//   -1 fill (nontemporal: don't thrash L2 with a 67 MB stream), counts, and
//   a global stash; then release-fence + atomicAdd(done). The LAST block to
//   arrive (exactly one; nobody waits/spins) acquires and performs the whole
//   scatter: block-scan of 2048 counts into an LDS offset table, then ~12K
//   edge copies via binary search (48/thread, latency-hidden), plus an exact
//   ballot-recompute path for any count > kCap (never expected to trigger).
//   One kernel node + one 4-byte memset node per iteration.

namespace {
constexpr int kB = 4;
constexpr int kN = 2048;
constexpr int kP = kN * (kN - 1) / 2;              // 2096128
constexpr long long kTotal = (long long)kB * kP;   // 8384512
constexpr int kBlock = 256;
constexpr int kItems = 16;
constexpr int kChunk = kBlock * kItems;            // 4096
constexpr int kGrid = (int)(kTotal / kChunk);      // 2047 (exact)
constexpr float kCut2 = 25.0f;                     // 5.0^2
constexpr int kCap = 128;                          // stash slots per block
constexpr int kMaxOvf = 64;                        // overflow-block list size
}  // namespace

typedef int iv4 __attribute__((ext_vector_type(4)));  // nontemporal-compatible

// p in [0,P) -> (i,j), i<j, triu row-major. Closed-form sqrt guess + exact
// integer fixup. C(i) = i*(4095-i)/2. disc < 2^24 so float sqrt is tight.
__device__ __forceinline__ void decode_pair(int p, int& i, int& j) {
  float t = sqrtf((float)(16769025 - 8 * p));
  int ii = (int)((4095.0f - t) * 0.5f);
  ii = ii < 0 ? 0 : (ii > kN - 2 ? kN - 2 : ii);
  while (ii > 0 && (ii * (4095 - ii)) / 2 > p) --ii;
  while (ii < kN - 2 && ((ii + 1) * (4094 - ii)) / 2 <= p) ++ii;
  i = ii;
  j = ii + 1 + (p - (ii * (4095 - ii)) / 2);
}

__device__ __forceinline__ bool pair_test(const float* __restrict__ x, int b, int p,
                                          int& gi, int& gj) {
  int i, j;
  decode_pair(p, i, j);
  const float* xb = x + (size_t)b * kN * 3;
  float dx = xb[3 * i + 0] - xb[3 * j + 0];
  float dy = xb[3 * i + 1] - xb[3 * j + 1];
  float dz = xb[3 * i + 2] - xb[3 * j + 2];
  gi = b * kN + i;
  gj = b * kN + j;
  return dx * dx + dy * dy + dz * dz <= kCut2;
}

__global__ __launch_bounds__(kBlock) void fused_kernel(
    const float* __restrict__ x, uint32_t* __restrict__ counts,
    uint32_t* __restrict__ done, int2* __restrict__ stash,
    int* __restrict__ out) {
  const int t = threadIdx.x;
  const int wave = t >> 6, lane = t & 63;
  const int bid = blockIdx.x;
  const int base = bid * kChunk;

  __shared__ uint32_t slot[kItems * 4];  // 64 (item,wave) counts / scan
  __shared__ uint32_t wred[4];
  __shared__ uint32_t bcast;
  __shared__ uint32_t offs[kGrid + 1];   // finisher: 2048 x 4B = 8 KB
  __shared__ uint32_t totT;
  __shared__ int ovfl[kMaxOvf];
  __shared__ uint32_t novf;

  // ---- Phase A ----
  // -1 fill of this block's slice (4096 ints x 2 rows), NONTEMPORAL so the
  // 67 MB stream doesn't thrash L2 (x / counts stay hot).
  {
    const iv4 m1 = {-1, -1, -1, -1};
    iv4* o0 = (iv4*)out + (base >> 2);
    iv4* o1 = (iv4*)(out + kTotal) + (base >> 2);
#pragma unroll
    for (int s = 0; s < 4; ++s) {
      __builtin_nontemporal_store(m1, o0 + t + s * kBlock);
      __builtin_nontemporal_store(m1, o1 + t + s * kBlock);
    }
  }
  if (bid == 0 && t == 0) counts[kGrid] = 0;  // pad -> 2048 uint4-loadable

  // One sqrt-decode per thread, then incremental row-walk (+256/item).
  // (Validated structure: round-3 phase A, absmax 0.)
  int b = base / kP;
  int p = base - b * kP + t;
  if (p >= kP) { p -= kP; ++b; }
  int i, j;
  decode_pair(p, i, j);
  int ib = b * kN;

  const float3* __restrict__ x3 = (const float3*)x;
  float3 pi = x3[ib + i];

  uint32_t hits = 0;  // bit k = item k is an edge
#pragma unroll
  for (int k = 0; k < kItems; ++k) {
    float3 pj = x3[ib + j];
    float dx = pi.x - pj.x, dy = pi.y - pj.y, dz = pi.z - pj.z;
    if (dx * dx + dy * dy + dz * dz <= kCut2) hits |= (1u << k);
    if (k < kItems - 1) {
      j += kBlock;
      if (j >= kN) {  // row advance, mostly wave-coherent
        do {
          int ex = j - kN;
          ++i;
          if (i >= kN - 1) { i = 0; ib += kN; }
          j = i + 1 + ex;
        } while (j >= kN);
        pi = x3[ib + i];
      }
    }
  }

  if (t < kItems * 4) slot[t] = 0;
  __syncthreads();

  const bool waveany = (__ballot(hits != 0) != 0ULL);  // wave-uniform
  if (waveany) {
#pragma unroll
    for (int k = 0; k < kItems; ++k) {
      unsigned long long m = __ballot((hits >> k) & 1u);
      if (m != 0ULL && lane == 0) slot[k * 4 + wave] = (uint32_t)__popcll(m);
    }
  }
  __syncthreads();
  if (t < 64) {  // exclusive scan of 64 (item,wave) counts in one wave
    uint32_t v = slot[t];
    uint32_t run = v;
    for (int o = 1; o < 64; o <<= 1) {
      uint32_t u = __shfl_up(run, o, 64);
      if (lane >= o) run += u;
    }
    slot[t] = run - v;
    if (t == 63) counts[bid] = run;
  }
  __syncthreads();
  if (waveany) {
#pragma unroll
    for (int k = 0; k < kItems; ++k) {
      bool f = (hits >> k) & 1u;
      unsigned long long m = __ballot(f);
      if (m != 0ULL && f) {  // rare: ~6 hits per block expected
        int pf = base + k * kBlock + t;
        int hb = pf / kP;
        int hp = pf - hb * kP;
        int hi, hj;
        decode_pair(hp, hi, hj);
        uint32_t pos = slot[k * 4 + wave] +
                       (uint32_t)__popcll(m & ((1ULL << lane) - 1ULL));
        if (pos < (uint32_t)kCap)
          stash[(size_t)bid * kCap + pos] = make_int2(hb * kN + hi, hb * kN + hj);
      }
    }
  }

  // ---- Election: release our writes, count arrivals; last block finishes.
  __threadfence();  // release counts/stash/fill (device scope)
  __syncthreads();
  if (t == 0) bcast = atomicAdd(done, 1u);
  __syncthreads();
  if (bcast != (uint32_t)(kGrid - 1)) return;  // everyone else exits; no spin

  // ---- Finisher (exactly one block) ----
  __threadfence();  // acquire all blocks' counts/stash

  // Exclusive scan of 2048 counts into LDS offs[]; detect overflow blocks.
  uint32_t c[8];
  {
    const uint4* c4 = (const uint4*)counts;
    uint4 a = c4[t * 2 + 0];
    uint4 bb = c4[t * 2 + 1];
    c[0] = a.x; c[1] = a.y; c[2] = a.z; c[3] = a.w;
    c[4] = bb.x; c[5] = bb.y; c[6] = bb.z; c[7] = bb.w;
  }
  if (t == 0) novf = 0;
  uint32_t tsum = 0;
#pragma unroll
  for (int q = 0; q < 8; ++q) tsum += c[q];
  uint32_t run = tsum;  // wave-inclusive scan of per-thread sums
  for (int o = 1; o < 64; o <<= 1) {
    uint32_t u = __shfl_up(run, o, 64);
    if (lane >= o) run += u;
  }
  if (lane == 63) wred[wave] = run;
  __syncthreads();
  uint32_t wbase = 0;
  for (int w = 0; w < 4; ++w)
    if (w < wave) wbase += wred[w];
  uint32_t excl = wbase + run - tsum;  // this thread's exclusive base
#pragma unroll
  for (int q = 0; q < 8; ++q) {
    int idx = t * 8 + q;
    offs[idx] = excl;
    if (c[q] > (uint32_t)kCap) {
      uint32_t s_ = atomicAdd(&novf, 1u);
      if (s_ < (uint32_t)kMaxOvf) ovfl[s_] = idx;
    }
    excl += c[q];
  }
  if (t == 255) totT = excl;
  __syncthreads();
  const uint32_t T = totT;

  // Main copy: e-th edge -> owning block via binary search in LDS offs.
  for (uint32_t e = t; e < T; e += kBlock) {
    int lo = 0, hi = kGrid - 1;
    while (lo < hi) {
      int mid = (lo + hi + 1) >> 1;
      if (offs[mid] <= e) lo = mid; else hi = mid - 1;
    }
    uint32_t idx = e - offs[lo];
    if (idx < (uint32_t)kCap) {
      int2 v = stash[(size_t)lo * kCap + idx];
      out[e] = v.x;
      out[(size_t)kTotal + e] = v.y;
    }
  }
  __syncthreads();

  // Overflow blocks (count > kCap): exact ballot recompute, writes all of
  // that block's edges in order (idx < kCap duplicates are benign rewrites).
  uint32_t nov = novf;
  if (nov > (uint32_t)kMaxOvf) nov = (uint32_t)kMaxOvf;
  for (uint32_t o = 0; o < nov; ++o) {
    const int pb = ovfl[o];
    const int pbase = pb * kChunk;
    for (int k = 0; k < kItems; ++k) {
      int pf = pbase + k * kBlock + t;
      int hb = pf / kP, hp = pf - hb * kP;
      int gi_, gj_;
      bool f = pair_test(x, hb, hp, gi_, gj_);
      unsigned long long m = __ballot(f);
      if (lane == 0) slot[k * 4 + wave] = (uint32_t)__popcll(m);
    }
    __syncthreads();
    if (t < 64) {
      uint32_t v = slot[t];
      uint32_t r2 = v;
      for (int oo = 1; oo < 64; oo <<= 1) {
        uint32_t u = __shfl_up(r2, oo, 64);
        if (lane >= oo) r2 += u;
      }
      slot[t] = r2 - v;
    }
    __syncthreads();
    for (int k = 0; k < kItems; ++k) {
      int pf = pbase + k * kBlock + t;
      int hb = pf / kP, hp = pf - hb * kP;
      int gi_, gj_;
      bool f = pair_test(x, hb, hp, gi_, gj_);
      unsigned long long m = __ballot(f);
      if (f) {
        uint32_t pos = offs[pb] + slot[k * 4 + wave] +
                       (uint32_t)__popcll(m & ((1ULL << lane) - 1ULL));
        out[pos] = gi_;
        out[(size_t)kTotal + pos] = gj_;
      }
    }
    __syncthreads();
  }
}

extern "C" void kernel_launch(void* const* d_in, const int* in_sizes, int n_in,
                              void* d_out, int out_size, void* d_ws, size_t ws_size,
                              hipStream_t stream) {
  const float* x = (const float*)d_in[0];
  int* out = (int*)d_out;
  uint32_t* counts = (uint32_t*)d_ws;           // [2048] (1 pad)
  uint32_t* done = counts + 2048;               // [1] arrival counter
  int2* stash = (int2*)(counts + 2056);         // [2047 * kCap] ~2.1 MB

  (void)hipMemsetAsync(done, 0, sizeof(uint32_t), stream);  // graph-capturable
  hipLaunchKernelGGL(fused_kernel, dim3(kGrid), dim3(kBlock), 0, stream, x, counts,
                     done, stash, out);
}

// Round 6
// 51.101 us; speedup vs baseline: 6.3107x; 4.5665x over previous
//
#include <hip/hip_runtime.h>
#include <stdint.h>

// Radius-graph edge list, B=4, N=2048, cutoff 5.0.
// Output [2, B*P] int32: compacted valid edges (ascending flat index), -1 pad.
//
// Round-11: two dispatches, dependency-inverted.
//   Lessons so far (measured):
//     r3: cg::grid.sync  -> 286 us (L2 flush per barrier on 8 XCDs).
//     r5: single dispatch + per-block threadfence + nontemporal fill
//         -> 233 us (66 MB wrote at 287 GB/s; uncached/fence path is poison).
//     => the KERNEL BOUNDARY is the only cheap device-wide fence.
//     r7: prefix-before-fill serialized K2 -> +4 us. Fill must lead.
//   Structure:
//     K1 count_kernel  (2047 blk): pair tests only (validated r5 phase-A
//         walk, kItems=16) -> counts[2047]+pad, stash[<=128/blk].
//         ~0.2 MB writes, compute-bound, 3-6 us.
//     K2 fill_place    (2047 blk): (a) UNCONDITIONAL -1 fill of own 4096x2
//         slice -- zero dependencies, stores issue from cycle 0;
//         (b) meanwhile scan all 2048 counts (8 KB, L2-hot) into an LDS
//         offset table (validated r5 finisher scan); (c) __syncthreads
//         (drains fill stores), then overwrite the edges that LAND in this
//         block's slice via binary search (validated r5 finisher copy).
//         Same-block ordering via barrier; cross-block same-address writes
//         impossible by construction. No fences, no atomics.
//   Overflow (count > kCap=128, expected ~6/blk, never in practice): the
//   landing block re-walks the owning block's chunk serially for the idx-th
//   hit. Exact, deterministic.

namespace {
constexpr int kB = 4;
constexpr int kN = 2048;
constexpr int kP = kN * (kN - 1) / 2;              // 2096128
constexpr long long kTotal = (long long)kB * kP;   // 8384512
constexpr int kBlock = 256;
constexpr int kItems = 16;
constexpr int kChunk = kBlock * kItems;            // 4096
constexpr int kGrid = (int)(kTotal / kChunk);      // 2047 (exact)
constexpr float kCut2 = 25.0f;                     // 5.0^2
constexpr int kCap = 128;                          // stash slots per block
}  // namespace

// p in [0,P) -> (i,j), i<j, triu row-major. Closed-form sqrt guess + exact
// integer fixup. C(i) = i*(4095-i)/2. disc < 2^24 so float sqrt is tight.
__device__ __forceinline__ void decode_pair(int p, int& i, int& j) {
  float t = sqrtf((float)(16769025 - 8 * p));
  int ii = (int)((4095.0f - t) * 0.5f);
  ii = ii < 0 ? 0 : (ii > kN - 2 ? kN - 2 : ii);
  while (ii > 0 && (ii * (4095 - ii)) / 2 > p) --ii;
  while (ii < kN - 2 && ((ii + 1) * (4094 - ii)) / 2 <= p) ++ii;
  i = ii;
  j = ii + 1 + (p - (ii * (4095 - ii)) / 2);
}

__device__ __forceinline__ bool pair_test(const float* __restrict__ x, int b, int p,
                                          int& gi, int& gj) {
  int i, j;
  decode_pair(p, i, j);
  const float* xb = x + (size_t)b * kN * 3;
  float dx = xb[3 * i + 0] - xb[3 * j + 0];
  float dy = xb[3 * i + 1] - xb[3 * j + 1];
  float dz = xb[3 * i + 2] - xb[3 * j + 2];
  gi = b * kN + i;
  gj = b * kN + j;
  return dx * dx + dy * dy + dz * dz <= kCut2;
}

// ---------------------------------------------------------------------------
// K1: pair tests -> counts + stash. No output traffic. (r5 phase-A, validated)
// ---------------------------------------------------------------------------
__global__ __launch_bounds__(kBlock) void count_kernel(
    const float* __restrict__ x, uint32_t* __restrict__ counts,
    int2* __restrict__ stash) {
  const int t = threadIdx.x;
  const int wave = t >> 6, lane = t & 63;
  const int bid = blockIdx.x;
  const int base = bid * kChunk;

  __shared__ uint32_t slot[kItems * 4];  // 64 (item,wave) counts / scan

  if (bid == 0 && t == 0) counts[kGrid] = 0;  // pad -> 2048 uint4-loadable

  // One sqrt-decode per thread, then incremental row-walk (+256/item).
  int b = base / kP;
  int p = base - b * kP + t;
  if (p >= kP) { p -= kP; ++b; }
  int i, j;
  decode_pair(p, i, j);
  int ib = b * kN;

  const float3* __restrict__ x3 = (const float3*)x;
  float3 pi = x3[ib + i];

  uint32_t hits = 0;  // bit k = item k is an edge
#pragma unroll
  for (int k = 0; k < kItems; ++k) {
    float3 pj = x3[ib + j];
    float dx = pi.x - pj.x, dy = pi.y - pj.y, dz = pi.z - pj.z;
    if (dx * dx + dy * dy + dz * dz <= kCut2) hits |= (1u << k);
    if (k < kItems - 1) {
      j += kBlock;
      if (j >= kN) {  // row advance, mostly wave-coherent
        do {
          int ex = j - kN;
          ++i;
          if (i >= kN - 1) { i = 0; ib += kN; }
          j = i + 1 + ex;
        } while (j >= kN);
        pi = x3[ib + i];
      }
    }
  }

  if (t < kItems * 4) slot[t] = 0;
  __syncthreads();

  const bool waveany = (__ballot(hits != 0) != 0ULL);  // wave-uniform
  if (waveany) {
#pragma unroll
    for (int k = 0; k < kItems; ++k) {
      unsigned long long m = __ballot((hits >> k) & 1u);
      if (m != 0ULL && lane == 0) slot[k * 4 + wave] = (uint32_t)__popcll(m);
    }
  }
  __syncthreads();
  if (t < 64) {  // exclusive scan of 64 (item,wave) counts in one wave
    uint32_t v = slot[t];
    uint32_t run = v;
    for (int o = 1; o < 64; o <<= 1) {
      uint32_t u = __shfl_up(run, o, 64);
      if (lane >= o) run += u;
    }
    slot[t] = run - v;
    if (t == 63) counts[bid] = run;
  }
  __syncthreads();
  if (waveany) {
#pragma unroll
    for (int k = 0; k < kItems; ++k) {
      bool f = (hits >> k) & 1u;
      unsigned long long m = __ballot(f);
      if (m != 0ULL && f) {  // rare: ~6 hits per block expected
        int pf = base + k * kBlock + t;
        int hb = pf / kP;
        int hp = pf - hb * kP;
        int hi, hj;
        decode_pair(hp, hi, hj);
        uint32_t pos = slot[k * 4 + wave] +
                       (uint32_t)__popcll(m & ((1ULL << lane) - 1ULL));
        if (pos < (uint32_t)kCap)
          stash[(size_t)bid * kCap + pos] = make_int2(hb * kN + hi, hb * kN + hj);
      }
    }
  }
}

// ---------------------------------------------------------------------------
// K2: unconditional -1 fill (leads, zero deps) + distributed finisher: each
// block places the edges landing in its own slice. (scan/copy: r5, validated)
// ---------------------------------------------------------------------------
__global__ __launch_bounds__(kBlock) void fill_place_kernel(
    const float* __restrict__ x, const uint32_t* __restrict__ counts,
    const int2* __restrict__ stash, int* __restrict__ out) {
  const int t = threadIdx.x;
  const int wave = t >> 6, lane = t & 63;
  const int bid = blockIdx.x;
  const int base = bid * kChunk;

  __shared__ uint32_t offs[kGrid + 1];  // 2048 x 4B = 8 KB
  __shared__ uint32_t wred[4];
  __shared__ uint32_t totT;

  // (a) -1 fill of this block's slice (4096 ints x 2 rows), plain cached
  // stores, no dependencies -> issue from cycle 0, drain under (b).
  {
    const int4 m1 = make_int4(-1, -1, -1, -1);
    int4* o0 = (int4*)out + (base >> 2);
    int4* o1 = (int4*)(out + kTotal) + (base >> 2);
#pragma unroll
    for (int s = 0; s < 4; ++s) {
      o0[t + s * kBlock] = m1;
      o1[t + s * kBlock] = m1;
    }
  }

  // (b) scan all 2048 counts into LDS offs[] (8 KB, L2-hot; r5 finisher).
  uint32_t c[8];
  {
    const uint4* c4 = (const uint4*)counts;
    uint4 a = c4[t * 2 + 0];
    uint4 bb = c4[t * 2 + 1];
    c[0] = a.x; c[1] = a.y; c[2] = a.z; c[3] = a.w;
    c[4] = bb.x; c[5] = bb.y; c[6] = bb.z; c[7] = bb.w;
  }
  uint32_t tsum = 0;
#pragma unroll
  for (int q = 0; q < 8; ++q) tsum += c[q];
  uint32_t run = tsum;  // wave-inclusive scan of per-thread sums
  for (int o = 1; o < 64; o <<= 1) {
    uint32_t u = __shfl_up(run, o, 64);
    if (lane >= o) run += u;
  }
  if (lane == 63) wred[wave] = run;
  __syncthreads();
  uint32_t wbase = 0;
  for (int w = 0; w < 4; ++w)
    if (w < wave) wbase += wred[w];
  uint32_t excl = wbase + run - tsum;  // this thread's exclusive base
#pragma unroll
  for (int q = 0; q < 8; ++q) {
    offs[t * 8 + q] = excl;
    excl += c[q];
  }
  if (t == 255) totT = excl;
  // (c) barrier: orders the -1 fill stores before the edge overwrites below
  // (same block, same XCD L2 -> later store wins), and publishes offs/totT.
  __syncthreads();
  const uint32_t T = totT;

  // Edges landing in THIS slice: e in [base, base+kChunk) ∩ [0, T).
  uint32_t e_end = (uint32_t)(base + kChunk);
  if (e_end > T) e_end = T;
  for (uint32_t e = base + t; e < e_end; e += kBlock) {
    // Owning count-block: largest lo with offs[lo] <= e (offs nondecreasing).
    int lo = 0, hi = kGrid - 1;
    while (lo < hi) {
      int mid = (lo + hi + 1) >> 1;
      if (offs[mid] <= e) lo = mid; else hi = mid - 1;
    }
    uint32_t idx = e - offs[lo];
    int2 v;
    if (idx < (uint32_t)kCap) {
      v = stash[(size_t)lo * kCap + idx];
    } else {
      // Never-path (count > kCap): serial re-walk of block lo's chunk for
      // its idx-th hit. Exact.
      v = make_int2(-1, -1);
      uint32_t seen = 0;
      const int obase = lo * kChunk;
      for (int q = 0; q < kChunk; ++q) {
        int pf = obase + q;
        int hb = pf / kP, hp = pf - hb * kP;
        int gi_, gj_;
        if (pair_test(x, hb, hp, gi_, gj_)) {
          if (seen == idx) { v = make_int2(gi_, gj_); break; }
          ++seen;
        }
      }
    }
    out[e] = v.x;
    out[(size_t)kTotal + e] = v.y;
  }
}

extern "C" void kernel_launch(void* const* d_in, const int* in_sizes, int n_in,
                              void* d_out, int out_size, void* d_ws, size_t ws_size,
                              hipStream_t stream) {
  const float* x = (const float*)d_in[0];
  int* out = (int*)d_out;
  uint32_t* counts = (uint32_t*)d_ws;           // [2048] (incl. 1 pad)
  int2* stash = (int2*)(counts + 2048);         // [2047 * kCap] ~2.1 MB

  hipLaunchKernelGGL(count_kernel, dim3(kGrid), dim3(kBlock), 0, stream, x, counts,
                     stash);
  hipLaunchKernelGGL(fill_place_kernel, dim3(kGrid), dim3(kBlock), 0, stream, x,
                     counts, stash, out);
}

// Round 7
// 32.460 us; speedup vs baseline: 9.9349x; 1.5743x over previous
//
#include <hip/hip_runtime.h>
#include <stdint.h>

// Radius-graph edge list, B=4, N=2048, cutoff 5.0.
// Output [2, B*P] int32: compacted valid edges (ascending flat index), -1 pad.
//
// Round-12: EXACT round-0 structure (32.6 us, best measured) + ONE change:
// scatter blocks load their own count FIRST and early-exit if zero. In r0,
// all 4094 scatter blocks read the full 16 KB counts array (64 MB aggregate
// L2) for a prefix only ~3 blocks need. Now 4091/4094 blocks do one
// broadcast 4B load and retire.
//
// Measured lessons pinned:
//   r3: cg::grid.sync = 286 us (L2 flush per barrier on 8 XCDs).
//   r5: nontemporal fill + per-block threadfence = 233 us (287 GB/s writes).
//   r6: barrier right after the 67 MB fill = +20 us (syncthreads forces
//       vmcnt(0): block waits for its fill to fully drain with nothing to
//       hide it). Fill must be followed by long independent work (r0 pass1).
//   r1/r2/r7-variants: moving fill/prefix across kernels never beats r0.

namespace {
constexpr int kB = 4;
constexpr int kN = 2048;
constexpr int kP = kN * (kN - 1) / 2;              // 2096128
constexpr long long kTotal = (long long)kB * kP;   // 8384512
constexpr int kBlock = 256;
constexpr int kItems = 8;
constexpr int kChunk = kBlock * kItems;            // 2048
constexpr int kNBlk = (int)(kTotal / kChunk);      // 4094 (exact, no tail)
constexpr float kCut2 = 25.0f;                     // 5.0^2
constexpr int kCap = 128;                          // stash slots per block
}  // namespace

// p in [0,P) -> (i,j), i<j, triu row-major. Closed-form sqrt guess + exact
// integer fixup. C(i) = i*(4095-i)/2. disc < 2^24 so float sqrt is tight.
__device__ __forceinline__ void decode_pair(int p, int& i, int& j) {
  float t = sqrtf((float)(16769025 - 8 * p));
  int ii = (int)((4095.0f - t) * 0.5f);
  ii = ii < 0 ? 0 : (ii > kN - 2 ? kN - 2 : ii);
  while (ii > 0 && (ii * (4095 - ii)) / 2 > p) --ii;
  while (ii < kN - 2 && ((ii + 1) * (4094 - ii)) / 2 <= p) ++ii;
  i = ii;
  j = ii + 1 + (p - (ii * (4095 - ii)) / 2);
}

__device__ __forceinline__ bool pair_test(const float* __restrict__ x, int b, int p,
                                          int& gi, int& gj) {
  int i, j;
  decode_pair(p, i, j);
  const float* xb = x + (size_t)b * kN * 3;
  float dx = xb[3 * i + 0] - xb[3 * j + 0];
  float dy = xb[3 * i + 1] - xb[3 * j + 1];
  float dz = xb[3 * i + 2] - xb[3 * j + 2];
  gi = b * kN + i;
  gj = b * kN + j;
  return dx * dx + dy * dy + dz * dz <= kCut2;
}

__global__ __launch_bounds__(kBlock) void pass1_kernel(const float* __restrict__ x,
                                                       uint32_t* __restrict__ counts,
                                                       int2* __restrict__ stash,
                                                       int* __restrict__ out) {
  const int t = threadIdx.x;
  const int wave = t >> 6, lane = t & 63;
  const int bid = blockIdx.x;
  const int base = bid * kChunk;

  // Fill this block's slice of both output rows with -1 (2048 ints each).
  // Zero-dependency stores: issue from cycle 0, drain under the compute.
  {
    const int4 m1 = make_int4(-1, -1, -1, -1);
    int4* o0 = (int4*)out + (base >> 2);
    int4* o1 = (int4*)(out + kTotal) + (base >> 2);
    o0[t] = m1;
    o0[t + kBlock] = m1;
    o1[t] = m1;
    o1[t + kBlock] = m1;
  }
  if (bid == 0 && t < 2) counts[kNBlk + t] = 0;  // pad so scatter can uint4-load

  // One sqrt-decode per thread per block, then incremental row-walk (+256/item).
  int b = base / kP;
  int p = base - b * kP + t;
  if (p >= kP) { p -= kP; ++b; }
  int i, j;
  decode_pair(p, i, j);
  int ib = b * kN;  // point-index base of batch b

  const float3* __restrict__ x3 = (const float3*)x;
  float3 pi = x3[ib + i];

  uint32_t hits = 0;  // bit k = item k is an edge
#pragma unroll
  for (int k = 0; k < kItems; ++k) {
    float3 pj = x3[ib + j];
    float dx = pi.x - pj.x, dy = pi.y - pj.y, dz = pi.z - pj.z;
    if (dx * dx + dy * dy + dz * dz <= kCut2) hits |= (1u << k);
    if (k < kItems - 1) {
      j += kBlock;
      if (j >= kN) {  // ~20% of items, mostly wave-coherent
        do {
          int ex = j - kN;
          ++i;
          if (i >= kN - 1) { i = 0; ib += kN; }
          j = i + 1 + ex;
        } while (j >= kN);
        pi = x3[ib + i];
      }
    }
  }

  __shared__ uint32_t slot[32];
  if (t < 32) slot[t] = 0;
  __syncthreads();

  const bool waveany = (__ballot(hits != 0) != 0ULL);  // wave-uniform
  if (waveany) {
#pragma unroll
    for (int k = 0; k < kItems; ++k) {
      unsigned long long m = __ballot((hits >> k) & 1u);
      if (m != 0ULL && lane == 0) slot[k * 4 + wave] = (uint32_t)__popcll(m);
    }
  }
  __syncthreads();
  if (t < 32) {  // exclusive scan of 32 (item,wave) counts; write block total
    uint32_t v = slot[t];
    uint32_t run = v;
    for (int off = 1; off < 32; off <<= 1) {
      uint32_t u = __shfl_up(run, off, 64);
      if (t >= off) run += u;
    }
    slot[t] = run - v;
    if (t == 31) counts[bid] = run;
  }
  __syncthreads();
  if (waveany) {
#pragma unroll
    for (int k = 0; k < kItems; ++k) {
      bool f = (hits >> k) & 1u;
      unsigned long long m = __ballot(f);
      if (m != 0ULL && f) {  // rare: ~3 hits per block total
        int pf = base + k * kBlock + t;
        int hb = pf / kP;
        int hp = pf - hb * kP;
        int hi, hj;
        decode_pair(hp, hi, hj);
        uint32_t pos = slot[k * 4 + wave] +
                       (uint32_t)__popcll(m & ((1ULL << lane) - 1ULL));
        if (pos < (uint32_t)kCap)
          stash[(size_t)bid * kCap + pos] = make_int2(hb * kN + hi, hb * kN + hj);
      }
    }
  }
}

__global__ __launch_bounds__(kBlock) void scatter_kernel(const float* __restrict__ x,
                                                         const uint32_t* __restrict__ counts,
                                                         const int2* __restrict__ stash,
                                                         int* __restrict__ out) {
  const int bid = blockIdx.x;
  const int t = threadIdx.x;

  // NEW (r12): own count first; ~4091/4094 blocks exit on one broadcast load
  // instead of reading the full 16 KB counts array for an unused prefix.
  const uint32_t cnt = counts[bid];
  if (cnt == 0) return;

  // Self-service prefix: offset = sum(counts[idx < bid]), from 16 KB L2-hot.
  const uint4* c4 = (const uint4*)counts;  // [4096] incl. zero pad
  uint32_t part = 0;
#pragma unroll
  for (int q = 0; q < 4; ++q) {
    uint4 v = c4[t * 4 + q];
    int i0 = t * 16 + q * 4;
    part += (i0 + 0 < bid) ? v.x : 0u;
    part += (i0 + 1 < bid) ? v.y : 0u;
    part += (i0 + 2 < bid) ? v.z : 0u;
    part += (i0 + 3 < bid) ? v.w : 0u;
  }
  for (int o = 32; o > 0; o >>= 1) part += __shfl_down(part, o, 64);
  __shared__ uint32_t wred[4];
  if ((t & 63) == 0) wred[t >> 6] = part;
  __syncthreads();
  if (t == 0) wred[0] = wred[0] + wred[1] + wred[2] + wred[3];
  __syncthreads();
  const uint32_t off = wred[0];

  if (cnt <= (uint32_t)kCap) {
    for (uint32_t e = t; e < cnt; e += kBlock) {
      int2 v = stash[(size_t)bid * kCap + e];
      out[off + e] = v.x;
      out[(size_t)kTotal + off + e] = v.y;
    }
    return;
  }
  // Overflow fallback (count > kCap): recompute this block's edges with
  // ballot ranks and write directly. Deterministic + exact.
  const int wave = t >> 6, lane = t & 63;
  const int base = bid * kChunk;
  const int bb0 = base / kP;
  const int p0 = base - bb0 * kP;
  __shared__ uint32_t slot[kItems * 4];
  unsigned long long masks[kItems];
  int gi[kItems], gj[kItems];
  bool fl[kItems];
  for (int k = 0; k < kItems; ++k) {
    int o = k * kBlock + t;
    int b = bb0, p = p0 + o;
    if (p >= kP) { p -= kP; ++b; }
    fl[k] = pair_test(x, b, p, gi[k], gj[k]);
    masks[k] = __ballot(fl[k]);
    if (lane == 0) slot[k * 4 + wave] = (uint32_t)__popcll(masks[k]);
  }
  __syncthreads();
  if (t == 0) {
    uint32_t run = 0;
    for (int s = 0; s < kItems * 4; ++s) {
      uint32_t c = slot[s];
      slot[s] = run;
      run += c;
    }
  }
  __syncthreads();
  for (int k = 0; k < kItems; ++k) {
    if (fl[k]) {
      uint32_t pos = off + slot[k * 4 + wave] +
                     (uint32_t)__popcll(masks[k] & ((1ULL << lane) - 1ULL));
      out[pos] = gi[k];
      out[(size_t)kTotal + pos] = gj[k];
    }
  }
}

extern "C" void kernel_launch(void* const* d_in, const int* in_sizes, int n_in,
                              void* d_out, int out_size, void* d_ws, size_t ws_size,
                              hipStream_t stream) {
  const float* x = (const float*)d_in[0];
  int* out = (int*)d_out;
  uint32_t* counts = (uint32_t*)d_ws;                 // [4096] (2 pad)
  int2* stash = (int2*)(counts + 4096);               // [4094 * kCap] ~4.2 MB

  hipLaunchKernelGGL(pass1_kernel, dim3(kNBlk), dim3(kBlock), 0, stream, x, counts,
                     stash, out);
  hipLaunchKernelGGL(scatter_kernel, dim3(kNBlk), dim3(kBlock), 0, stream, x, counts,
                     stash, out);
}